// Round 1
// baseline (81.130 us; speedup 1.0000x reference)
//
#include <hip/hip_runtime.h>
#include <hip/hip_bf16.h>
#include <stdint.h>

#define B_ 4
#define M_ 4096
#define N_ 4096
#define D_ 256

typedef __attribute__((ext_vector_type(8))) short bf16x8;
typedef __attribute__((ext_vector_type(4))) float f32x4;

// RNE float->bf16 (no NaN in this data)
__device__ inline unsigned short f2bf(float f) {
    unsigned int u = __float_as_uint(f);
    return (unsigned short)((u + 0x7fffu + ((u >> 16) & 1u)) >> 16);
}

// One wave per row: compute 1/||row||, scale, convert to bf16.
__global__ __launch_bounds__(256) void norm_cvt(const float* __restrict__ x,
                                                const float* __restrict__ y,
                                                ushort* __restrict__ xb,
                                                ushort* __restrict__ yb) {
    int gw   = (blockIdx.x * 256 + threadIdx.x) >> 6;  // row id across both tensors
    int lane = threadIdx.x & 63;
    const int R = B_ * 4096;
    const float* src;
    ushort* dst;
    if (gw < R) { src = x + (size_t)gw * D_;        dst = xb + (size_t)gw * D_; }
    else        { src = y + (size_t)(gw - R) * D_;  dst = yb + (size_t)(gw - R) * D_; }

    float4 v = reinterpret_cast<const float4*>(src)[lane];   // 64 lanes * 4 = 256
    float ss = v.x * v.x + v.y * v.y + v.z * v.z + v.w * v.w;
#pragma unroll
    for (int off = 32; off; off >>= 1) ss += __shfl_xor(ss, off);
    float scale = ss > 0.f ? rsqrtf(ss) : 0.f;

    ushort4 o;
    o.x = f2bf(v.x * scale);
    o.y = f2bf(v.y * scale);
    o.z = f2bf(v.z * scale);
    o.w = f2bf(v.w * scale);
    reinterpret_cast<ushort4*>(dst)[lane] = o;
}

// C[b][m][n] = sum_d Yb[b][m][d] * Xb[b][n][d]   (both row-major = A*B^T GEMM)
// 128x128 tile, 4 waves (2x2 of 64x64), BK=64 double-buffered LDS,
// global_load_lds(16B) staging with inverse-swizzled source, XOR-swizzled reads.
__global__ __launch_bounds__(256) void cosgemm(const ushort* __restrict__ Xb,
                                               const ushort* __restrict__ Yb,
                                               float* __restrict__ out) {
    // LDS: [2 bufs][ A:128x64 | B:128x64 ] bf16 = 64 KiB
    __shared__ char smem[65536];

    const int tid  = threadIdx.x;
    const int w    = tid >> 6;
    const int lane = tid & 63;

    // XCD-aware bijective swizzle: 4096 blocks, 8 XCDs, 512 per XCD chunk
    int bid = blockIdx.x;
    int swz = ((bid & 7) << 9) | (bid >> 3);
    int b   = swz >> 10;          // batch
    int t   = swz & 1023;
    int tm  = (t >> 5) << 7;      // tile row base (y rows / output m)
    int tn  = (t & 31) << 7;      // tile col base (x rows / output n)

    const ushort* Ag = Yb + ((size_t)b * M_ + tm) * D_;
    const ushort* Bg = Xb + ((size_t)b * N_ + tn) * D_;

    // staging: chunk c (1 KiB) = rows 8c..8c+7 of the 128x64 tile.
    // LDS dest is linear (base + lane*16); source d-slot pre-swizzled so that
    // LDS slot s of row r holds global slot s ^ (r&7).
    const int srow  = lane >> 3;              // row within chunk (= row&7)
    const int gslot = (lane & 7) ^ srow;      // inverse-swizzled source slot

    auto stage = [&](int buf, int k0) {
        char* base = smem + buf * 32768;
#pragma unroll
        for (int i = 0; i < 4; ++i) {
            int c = i * 4 + w;                 // 16 chunks over 4 waves
            const ushort* ga = Ag + (size_t)(c * 8 + srow) * D_ + k0 + gslot * 8;
            __builtin_amdgcn_global_load_lds(
                (const __attribute__((address_space(1))) void*)ga,
                (__attribute__((address_space(3))) void*)(base + c * 1024), 16, 0, 0);
            const ushort* gb = Bg + (size_t)(c * 8 + srow) * D_ + k0 + gslot * 8;
            __builtin_amdgcn_global_load_lds(
                (const __attribute__((address_space(1))) void*)gb,
                (__attribute__((address_space(3))) void*)(base + 16384 + c * 1024), 16, 0, 0);
        }
    };

    const int wr = (w >> 1) << 6;   // wave's 64-row block
    const int wc = (w & 1) << 6;    // wave's 64-col block

    f32x4 acc[4][4] = {};

    stage(0, 0);
    __syncthreads();

#pragma unroll
    for (int s = 0; s < 4; ++s) {
        const int buf = s & 1;
        if (s < 3) stage(buf ^ 1, (s + 1) * 64);
        const char* Abase = smem + buf * 32768;
        const char* Bbase = Abase + 16384;
#pragma unroll
        for (int ks = 0; ks < 2; ++ks) {
            // fragment: 16B from row (l&15) at k-slot ks*4+(l>>4); read swizzled
            const int colb = ((ks * 4 + (lane >> 4)) ^ (lane & 7)) << 4;
            bf16x8 af[4], bf[4];
#pragma unroll
            for (int m = 0; m < 4; ++m) {
                int row = wr + m * 16 + (lane & 15);
                af[m] = *reinterpret_cast<const bf16x8*>(Abase + row * 128 + colb);
            }
#pragma unroll
            for (int n = 0; n < 4; ++n) {
                int row = wc + n * 16 + (lane & 15);
                bf[n] = *reinterpret_cast<const bf16x8*>(Bbase + row * 128 + colb);
            }
#pragma unroll
            for (int m = 0; m < 4; ++m)
#pragma unroll
                for (int n = 0; n < 4; ++n)
                    acc[m][n] = __builtin_amdgcn_mfma_f32_16x16x32_bf16(
                        af[m], bf[n], acc[m][n], 0, 0, 0);
        }
        __syncthreads();
    }

    // C/D layout: col = lane&15, row = (lane>>4)*4 + reg   [m89-verified]
    const int rj = (lane >> 4) << 2;
    const int cj = lane & 15;
#pragma unroll
    for (int m = 0; m < 4; ++m) {
#pragma unroll
        for (int j = 0; j < 4; ++j) {
            size_t r = (size_t)(tm + wr + m * 16 + rj + j);
            float* rowp = out + ((size_t)b * M_ + r) * N_ + tn + wc + cj;
#pragma unroll
            for (int n = 0; n < 4; ++n)
                rowp[n * 16] = acc[m][n][j];
        }
    }
}

extern "C" void kernel_launch(void* const* d_in, const int* in_sizes, int n_in,
                              void* d_out, int out_size, void* d_ws, size_t ws_size,
                              hipStream_t stream) {
    const float* x = (const float*)d_in[0];   // [4,4096,256] f32
    const float* y = (const float*)d_in[1];   // [4,4096,256] f32
    float* out = (float*)d_out;               // [4,4096,4096] f32

    ushort* xb = (ushort*)d_ws;                       // bf16 normalized x
    ushort* yb = xb + (size_t)B_ * N_ * D_;           // bf16 normalized y

    norm_cvt<<<8192, 256, 0, stream>>>(x, y, xb, yb); // 32768 rows, 4 waves/block
    cosgemm<<<4096, 256, 0, stream>>>(xb, yb, out);   // 4 batches * 32*32 tiles
}

// Round 2
// 76.062 us; speedup vs baseline: 1.0666x; 1.0666x over previous
//
#include <hip/hip_runtime.h>
#include <hip/hip_bf16.h>
#include <stdint.h>

#define B_ 4
#define M_ 4096
#define N_ 4096
#define D_ 256

typedef __attribute__((ext_vector_type(8))) short bf16x8;
typedef __attribute__((ext_vector_type(4))) float f32x4;

// RNE float->bf16 (no NaN in this data)
__device__ inline unsigned short f2bf(float f) {
    unsigned int u = __float_as_uint(f);
    return (unsigned short)((u + 0x7fffu + ((u >> 16) & 1u)) >> 16);
}

// One wave per row: compute 1/||row||, scale, convert to bf16.
__global__ __launch_bounds__(256) void norm_cvt(const float* __restrict__ x,
                                                const float* __restrict__ y,
                                                ushort* __restrict__ xb,
                                                ushort* __restrict__ yb) {
    int gw   = (blockIdx.x * 256 + threadIdx.x) >> 6;  // row id across both tensors
    int lane = threadIdx.x & 63;
    const int R = B_ * 4096;
    const float* src;
    ushort* dst;
    if (gw < R) { src = x + (size_t)gw * D_;        dst = xb + (size_t)gw * D_; }
    else        { src = y + (size_t)(gw - R) * D_;  dst = yb + (size_t)(gw - R) * D_; }

    float4 v = reinterpret_cast<const float4*>(src)[lane];   // 64 lanes * 4 = 256
    float ss = v.x * v.x + v.y * v.y + v.z * v.z + v.w * v.w;
#pragma unroll
    for (int off = 32; off; off >>= 1) ss += __shfl_xor(ss, off);
    float scale = ss > 0.f ? rsqrtf(ss) : 0.f;

    ushort4 o;
    o.x = f2bf(v.x * scale);
    o.y = f2bf(v.y * scale);
    o.z = f2bf(v.z * scale);
    o.w = f2bf(v.w * scale);
    reinterpret_cast<ushort4*>(dst)[lane] = o;
}

// C[b][m][n] = sum_d Yb[b][m][d] * Xb[b][n][d]   (both row-major = A*B^T GEMM)
// 128x128 tile, 4 waves (2x2 of 64x64), BK=64 double-buffered LDS,
// global_load_lds(16B) staging with inverse-swizzled source, XOR-swizzled reads.
// K-loop sync: counted vmcnt(8) (T4) — stage(s+1)'s loads stay in flight
// across the barrier; only stage(s)'s 8 loads are drained per step.
__global__ __launch_bounds__(256) void cosgemm(const ushort* __restrict__ Xb,
                                               const ushort* __restrict__ Yb,
                                               float* __restrict__ out) {
    // LDS: [2 bufs][ A:128x64 | B:128x64 ] bf16 = 64 KiB  -> 2 blocks/CU
    __shared__ char smem[65536];

    const int tid  = threadIdx.x;
    const int w    = tid >> 6;
    const int lane = tid & 63;

    // XCD-aware bijective swizzle: 4096 blocks, 8 XCDs, 512 per XCD chunk
    int bid = blockIdx.x;
    int swz = ((bid & 7) << 9) | (bid >> 3);
    int b   = swz >> 10;          // batch
    int t   = swz & 1023;
    int tm  = (t >> 5) << 7;      // tile row base (y rows / output m)
    int tn  = (t & 31) << 7;      // tile col base (x rows / output n)

    const ushort* Ag = Yb + ((size_t)b * M_ + tm) * D_;
    const ushort* Bg = Xb + ((size_t)b * N_ + tn) * D_;

    // staging: chunk c (1 KiB) = rows 8c..8c+7 of the 128x64 tile.
    // LDS dest is linear (base + lane*16); source d-slot pre-swizzled so that
    // LDS slot s of row r holds global slot s ^ (r&7).
    const int srow  = lane >> 3;              // row within chunk (= row&7)
    const int gslot = (lane & 7) ^ srow;      // inverse-swizzled source slot

    auto stage = [&](int buf, int k0) {
        char* base = smem + buf * 32768;
#pragma unroll
        for (int i = 0; i < 4; ++i) {
            int c = i * 4 + w;                 // 16 chunks over 4 waves
            const ushort* ga = Ag + (size_t)(c * 8 + srow) * D_ + k0 + gslot * 8;
            __builtin_amdgcn_global_load_lds(
                (const __attribute__((address_space(1))) void*)ga,
                (__attribute__((address_space(3))) void*)(base + c * 1024), 16, 0, 0);
            const ushort* gb = Bg + (size_t)(c * 8 + srow) * D_ + k0 + gslot * 8;
            __builtin_amdgcn_global_load_lds(
                (const __attribute__((address_space(1))) void*)gb,
                (__attribute__((address_space(3))) void*)(base + 16384 + c * 1024), 16, 0, 0);
        }
    };

    const int wr = (w >> 1) << 6;   // wave's 64-row block
    const int wc = (w & 1) << 6;    // wave's 64-col block

    f32x4 acc[4][4] = {};

    stage(0, 0);                    // 8 loads/wave in flight

#pragma unroll
    for (int s = 0; s < 4; ++s) {
        const int buf = s & 1;
        // barrier 1: all waves done READING buf[s^1] (previous step) -> safe
        // to overwrite it with stage(s+1). Iter 0: trivially safe.
        __builtin_amdgcn_s_barrier();
        if (s < 3) {
            stage(buf ^ 1, (s + 1) * 64);   // +8 loads/wave in flight
            // drain stage(s)'s 8 loads only; stage(s+1)'s 8 stay in flight
            asm volatile("s_waitcnt vmcnt(8)" ::: "memory");
        } else {
            asm volatile("s_waitcnt vmcnt(0)" ::: "memory");
        }
        // barrier 2: every wave has its buf[s] loads complete -> tile ready
        __builtin_amdgcn_s_barrier();
        __builtin_amdgcn_sched_barrier(0);

        const char* Abase = smem + buf * 32768;
        const char* Bbase = Abase + 16384;
#pragma unroll
        for (int ks = 0; ks < 2; ++ks) {
            // fragment: 16B from row (l&15) at k-slot ks*4+(l>>4); read swizzled
            const int colb = ((ks * 4 + (lane >> 4)) ^ (lane & 7)) << 4;
            bf16x8 af[4], bf[4];
#pragma unroll
            for (int m = 0; m < 4; ++m) {
                int row = wr + m * 16 + (lane & 15);
                af[m] = *reinterpret_cast<const bf16x8*>(Abase + row * 128 + colb);
            }
#pragma unroll
            for (int n = 0; n < 4; ++n) {
                int row = wc + n * 16 + (lane & 15);
                bf[n] = *reinterpret_cast<const bf16x8*>(Bbase + row * 128 + colb);
            }
#pragma unroll
            for (int m = 0; m < 4; ++m)
#pragma unroll
                for (int n = 0; n < 4; ++n)
                    acc[m][n] = __builtin_amdgcn_mfma_f32_16x16x32_bf16(
                        af[m], bf[n], acc[m][n], 0, 0, 0);
        }
    }

    // C/D layout: col = lane&15, row = (lane>>4)*4 + reg   [m89-verified]
    const int rj = (lane >> 4) << 2;
    const int cj = lane & 15;
#pragma unroll
    for (int m = 0; m < 4; ++m) {
#pragma unroll
        for (int j = 0; j < 4; ++j) {
            size_t r = (size_t)(tm + wr + m * 16 + rj + j);
            float* rowp = out + ((size_t)b * M_ + r) * N_ + tn + wc + cj;
#pragma unroll
            for (int n = 0; n < 4; ++n)
                rowp[n * 16] = acc[m][n][j];
        }
    }
}

extern "C" void kernel_launch(void* const* d_in, const int* in_sizes, int n_in,
                              void* d_out, int out_size, void* d_ws, size_t ws_size,
                              hipStream_t stream) {
    const float* x = (const float*)d_in[0];   // [4,4096,256] f32
    const float* y = (const float*)d_in[1];   // [4,4096,256] f32
    float* out = (float*)d_out;               // [4,4096,4096] f32

    ushort* xb = (ushort*)d_ws;                       // bf16 normalized x
    ushort* yb = xb + (size_t)B_ * N_ * D_;           // bf16 normalized y

    norm_cvt<<<8192, 256, 0, stream>>>(x, y, xb, yb); // 32768 rows, 4 waves/block
    cosgemm<<<4096, 256, 0, stream>>>(xb, yb, out);   // 4 batches * 32*32 tiles
}